// Round 1
// baseline (34140.701 us; speedup 1.0000x reference)
//
#include <hip/hip_runtime.h>
#include <hip/hip_bf16.h>

// Problem constants (S,B,D,H,T) = (4,512,256,1024,50)
#define S_ 4
#define B_ 512
#define D_ 256
#define H_ 1024
#define T_ 50
#define M_ (S_*B_)   // 2048 rows total

#define LDH (H_ + 8)   // padded LDS row stride for h1/h2 (bf16 elems)
#define LDU (D_ + 8)   // padded LDS row stride for u

typedef __attribute__((ext_vector_type(8))) __bf16 bf16x8;
typedef __attribute__((ext_vector_type(4))) float  f32x4;

// NaN-free fast tanh: saturates to +/-1, ~1e-6 abs error (<< bf16 eps)
__device__ __forceinline__ float fast_tanh(float x) {
  const float e = __expf(2.f * x);
  return 1.f - 2.f / (e + 1.f);
}

// ---------------------------------------------------------------------------
// Runtime dtype detection + dt table + reg_state zeros.
//   flags[0] = weights/first_point/output are f32 (1) or bf16 (0)
//   flags[1] = time grid is f32 (1) or bf16 (0)
// ---------------------------------------------------------------------------
__global__ void detect_k(const void* t_raw, const void* w2_raw,
                         float* dts, int* flags, void* out) {
  __shared__ int cnt;
  const int l = threadIdx.x;           // 64 threads, 1 block
  if (l == 0) cnt = 0;
  __syncthreads();
  const unsigned short* u = (const unsigned short*)w2_raw;
  int c = 0;
  #pragma unroll
  for (int j = 0; j < 4; ++j) {
    const unsigned short v = u[l * 4 + j];
    const unsigned e = (v >> 7) & 0xFF;          // bf16 exponent field
    if (e >= 128) c++;                            // |x| >= 2.0 or NaN/Inf
  }
  atomicAdd(&cnt, c);
  __syncthreads();
  const unsigned tw0 = *(const unsigned*)t_raw;
  const int t_is_f32 = (tw0 == 0u) ? 1 : 0;
  const int w_is_f32 = (cnt > 16) ? 1 : 0;
  if (l == 0) { flags[0] = w_is_f32; flags[1] = t_is_f32; }
  if (l < T_ - 1) {
    float t0, t1;
    if (t_is_f32) {
      const float* tf = (const float*)t_raw;
      t0 = tf[l]; t1 = tf[l + 1];
    } else {
      const __hip_bfloat16* tb = (const __hip_bfloat16*)t_raw;
      t0 = __bfloat162float(tb[l]); t1 = __bfloat162float(tb[l + 1]);
    }
    dts[l] = t1 - t0;
  }
  if (l < S_) {   // reg_state = 0
    const size_t ro = (size_t)M_ * T_ * D_ + l;
    if (w_is_f32) ((float*)out)[ro] = 0.f;
    else          ((__hip_bfloat16*)out)[ro] = __float2bfloat16(0.f);
  }
}

// ---------------------------------------------------------------------------
// transpose to bf16: dst[N][K] = bf16(src[K][N]); src dtype per flags[0]
// ---------------------------------------------------------------------------
__global__ void transpose_k(const void* __restrict__ src,
                            __hip_bfloat16* __restrict__ dst, int K, int N,
                            const int* __restrict__ flags) {
  __shared__ __hip_bfloat16 tile[32][33];
  const int f32 = flags[0];
  const int tx = threadIdx.x, ty = threadIdx.y;
  const int nb = blockIdx.x * 32, kb = blockIdx.y * 32;
  #pragma unroll
  for (int j = 0; j < 32; j += 8) {
    const size_t si = (size_t)(kb + ty + j) * N + nb + tx;
    tile[ty + j][tx] = f32 ? __float2bfloat16(((const float*)src)[si])
                           : ((const __hip_bfloat16*)src)[si];
  }
  __syncthreads();
  #pragma unroll
  for (int j = 0; j < 32; j += 8)
    dst[(size_t)(nb + ty + j) * K + kb + tx] = tile[tx][ty + j];
}

// ---------------------------------------------------------------------------
// biases -> fp32 workspace arrays
// ---------------------------------------------------------------------------
__global__ void prep_bias_k(const void* b1r, const void* b2r, const void* b3r,
                            float* bf1, float* bf2, float* bf3,
                            const int* flags) {
  const int i = blockIdx.x * 256 + threadIdx.x;   // H_ threads
  const int f32 = flags[0];
  bf1[i] = f32 ? ((const float*)b1r)[i]
               : __bfloat162float(((const __hip_bfloat16*)b1r)[i]);
  bf2[i] = f32 ? ((const float*)b2r)[i]
               : __bfloat162float(((const __hip_bfloat16*)b2r)[i]);
  if (i < D_)
    bf3[i] = f32 ? ((const float*)b3r)[i]
                 : __bfloat162float(((const __hip_bfloat16*)b3r)[i]);
}

// ---------------------------------------------------------------------------
// pack Wt[N][K] (row-major bf16) into per-wave fragment-major stream:
//   block index p = (w*KT + kk)*TPW + nt   (w = wave 0..7, KT = K/32)
//   within block: lane*16B = MFMA B-fragment of tile (n0=(w*TPW+nt)*16, k0=kk*32)
//     lane elems j: Wt[n0 + (lane&15)][kk*32 + (lane>>4)*8 + j]
// One thread copies one 16B fragment; grid sized exactly to N*K/8 threads.
// ---------------------------------------------------------------------------
__global__ void pack_k(const __hip_bfloat16* __restrict__ Wt,
                       __hip_bfloat16* __restrict__ P, int K, int TPW) {
  const int tid = blockIdx.x * 256 + threadIdx.x;
  const int lane = tid & 63;
  const int p = tid >> 6;
  const int KT = K >> 5;
  const int nt = p % TPW;
  const int kk = (p / TPW) % KT;
  const int w  = p / (TPW * KT);
  const int n  = (w * TPW + nt) * 16 + (lane & 15);
  const int ko = kk * 32 + (lane >> 4) * 8;
  *(bf16x8*)&P[(size_t)tid * 8] = *(const bf16x8*)&Wt[(size_t)n * K + ko];
}

// ---------------------------------------------------------------------------
// Per-wave GEMM over the packed weight stream.
//   out[16 x TPW*16] tile for this wave; A = 16 rows in LDS (row stride LDA).
//   B fragments stream linearly from global (packed), double-buffered in regs.
// ---------------------------------------------------------------------------
template <int KT, int TPW, int LDA>
__device__ __forceinline__ void gemm_wave(const __hip_bfloat16* lA,
                                          const __hip_bfloat16* BpW,
                                          int l16, int quad, f32x4* acc) {
  const bf16x8* __restrict__ b = (const bf16x8*)BpW + (quad * 16 + l16);
  const __hip_bfloat16* arow = &lA[l16 * LDA + quad * 8];
  bf16x8 bb[2][TPW];
  bf16x8 aa[2];
  #pragma unroll
  for (int nt = 0; nt < TPW; nt++) bb[0][nt] = b[nt * 64];
  aa[0] = *(const bf16x8*)arow;
  #pragma unroll
  for (int kk = 0; kk < KT; kk++) {
    if (kk + 1 < KT) {          // prefetch next K-slice while computing this one
      aa[(kk + 1) & 1] = *(const bf16x8*)(arow + (kk + 1) * 32);
      #pragma unroll
      for (int nt = 0; nt < TPW; nt++)
        bb[(kk + 1) & 1][nt] = b[((kk + 1) * TPW + nt) * 64];
    }
    #pragma unroll
    for (int nt = 0; nt < TPW; nt++)
      acc[nt] = __builtin_amdgcn_mfma_f32_16x16x32_bf16(
          aa[kk & 1], bb[kk & 1][nt], acc[nt], 0, 0, 0);
  }
}

// ---------------------------------------------------------------------------
// Persistent ODE kernel: 128 blocks x 16 rows, 512 threads (8 waves).
// Each block integrates its 16 rows through all T-1 RK4 steps.
//   - u/h1/h2 activations in LDS (bf16, padded rows)
//   - y, accb RK4 state in registers (MFMA C-layout positions are static)
//   - weights streamed from L2 each stage via packed fragment-major layout
//   - 3 __syncthreads per stage, zero inter-block communication
// ---------------------------------------------------------------------------
__global__ __launch_bounds__(512, 1) void ode_k(
    const void* __restrict__ fp_raw,
    const __hip_bfloat16* __restrict__ W1p,
    const __hip_bfloat16* __restrict__ W2p,
    const __hip_bfloat16* __restrict__ W3p,
    const float* __restrict__ bf1, const float* __restrict__ bf2,
    const float* __restrict__ bf3, const float* __restrict__ dts,
    const int* __restrict__ flags, void* __restrict__ out) {
  __shared__ __hip_bfloat16 uA[16 * LDU];
  __shared__ __hip_bfloat16 h1s[16 * LDH];
  __shared__ __hip_bfloat16 h2s[16 * LDH];

  const int tid = threadIdx.x;
  const int wave = tid >> 6, lane = tid & 63;
  const int l16 = lane & 15, quad = lane >> 4;
  const int m0 = blockIdx.x * 16;
  const int rb = quad * 4;                 // this lane's C-layout row base
  const int ofl = flags[0];

  // per-wave packed weight slice bases (bf16 elems): wave slice = KT*TPW*512
  const __hip_bfloat16* W1w = W1p + (size_t)wave * (8  * 8 * 512);
  const __hip_bfloat16* W2w = W2p + (size_t)wave * (32 * 8 * 512);
  const __hip_bfloat16* W3w = W3p + (size_t)wave * (32 * 2 * 512);

  // bias registers (match epilogue column mapping)
  float b1r[8], b2r[8], b3r[2];
  #pragma unroll
  for (int nt = 0; nt < 8; nt++) {
    b1r[nt] = bf1[wave * 128 + nt * 16 + l16];
    b2r[nt] = bf2[wave * 128 + nt * 16 + l16];
  }
  #pragma unroll
  for (int nt = 0; nt < 2; nt++) b3r[nt] = bf3[wave * 32 + nt * 16 + l16];

  // RK4 state in registers at this lane's L3 C-layout positions:
  //   (m = m0 + rb + r, d = wave*32 + nt*16 + l16)
  float yreg[2][4], ab[2][4];
  #pragma unroll
  for (int nt = 0; nt < 2; nt++) {
    const int d = wave * 32 + nt * 16 + l16;
    #pragma unroll
    for (int r = 0; r < 4; r++) {
      const int m = m0 + rb + r;
      const size_t si = (size_t)m * D_ + d;
      const float v = ofl ? ((const float*)fp_raw)[si]
                          : __bfloat162float(((const __hip_bfloat16*)fp_raw)[si]);
      yreg[nt][r] = v;
      ab[nt][r] = 0.f;
      uA[(rb + r) * LDU + d] = __float2bfloat16(v);   // stage0 u = y
      const size_t oo = ((size_t)m * T_) * D_ + d;    // traj[t=0] = y
      if (ofl) ((float*)out)[oo] = v;
      else     ((__hip_bfloat16*)out)[oo] = __float2bfloat16(v);
    }
  }
  __syncthreads();

  #pragma unroll 1
  for (int t = 0; t < T_ - 1; ++t) {
    const float dtv = dts[t];
    #pragma unroll 1
    for (int st4 = 0; st4 < 4; ++st4) {
      // ---- L1: h1 = tanh(u @ W1 + b1), K = 256 ----
      {
        f32x4 acc[8];
        #pragma unroll
        for (int i = 0; i < 8; i++) acc[i] = f32x4{0.f, 0.f, 0.f, 0.f};
        gemm_wave<8, 8, LDU>(uA, W1w, l16, quad, acc);
        #pragma unroll
        for (int nt = 0; nt < 8; nt++) {
          const int col = wave * 128 + nt * 16 + l16;
          #pragma unroll
          for (int r = 0; r < 4; r++)
            h1s[(rb + r) * LDH + col] =
                __float2bfloat16(fast_tanh(acc[nt][r] + b1r[nt]));
        }
      }
      __syncthreads();
      // ---- L2: h2 = tanh(h1 @ W2 + b2), K = 1024 ----
      {
        f32x4 acc[8];
        #pragma unroll
        for (int i = 0; i < 8; i++) acc[i] = f32x4{0.f, 0.f, 0.f, 0.f};
        gemm_wave<32, 8, LDH>(h1s, W2w, l16, quad, acc);
        #pragma unroll
        for (int nt = 0; nt < 8; nt++) {
          const int col = wave * 128 + nt * 16 + l16;
          #pragma unroll
          for (int r = 0; r < 4; r++)
            h2s[(rb + r) * LDH + col] =
                __float2bfloat16(fast_tanh(acc[nt][r] + b2r[nt]));
        }
      }
      __syncthreads();
      // ---- L3: k = h2 @ W3 + b3, K = 1024; RK4 bookkeeping in registers ----
      {
        f32x4 acc[2];
        #pragma unroll
        for (int i = 0; i < 2; i++) acc[i] = f32x4{0.f, 0.f, 0.f, 0.f};
        gemm_wave<32, 2, LDH>(h2s, W3w, l16, quad, acc);
        #pragma unroll
        for (int nt = 0; nt < 2; nt++) {
          const int d = wave * 32 + nt * 16 + l16;
          #pragma unroll
          for (int r = 0; r < 4; r++) {
            const float kv = acc[nt][r] + b3r[nt];
            float uv;
            if (st4 == 0) {
              ab[nt][r] = kv;            uv = yreg[nt][r] + 0.5f * dtv * kv;
            } else if (st4 == 1) {
              ab[nt][r] += 2.f * kv;     uv = yreg[nt][r] + 0.5f * dtv * kv;
            } else if (st4 == 2) {
              ab[nt][r] += 2.f * kv;     uv = yreg[nt][r] + dtv * kv;
            } else {
              const float yn =
                  yreg[nt][r] + (dtv * (1.f / 6.f)) * (ab[nt][r] + kv);
              yreg[nt][r] = yn;
              uv = yn;                   // next timestep stage0: u = y
              const size_t oo =
                  ((size_t)(m0 + rb + r) * T_ + (t + 1)) * D_ + d;
              if (ofl) ((float*)out)[oo] = yn;
              else     ((__hip_bfloat16*)out)[oo] = __float2bfloat16(yn);
            }
            uA[(rb + r) * LDU + d] = __float2bfloat16(uv);
          }
        }
      }
      __syncthreads();
    }
  }
}

// ---------------------------------------------------------------------------
extern "C" void kernel_launch(void* const* d_in, const int* in_sizes, int n_in,
                              void* d_out, int out_size, void* d_ws, size_t ws_size,
                              hipStream_t stream) {
  const void* fp   = d_in[0];
  const void* tarr = d_in[1];
  const void* W1   = d_in[2];
  const void* b1   = d_in[3];
  const void* W2   = d_in[4];
  const void* b2   = d_in[5];
  const void* W3   = d_in[6];
  const void* b3   = d_in[7];

  // workspace carve (~6.2 MB total, all bases 16B-aligned)
  char* ws = (char*)d_ws;
  __hip_bfloat16* W1p = (__hip_bfloat16*)ws; ws += (size_t)H_ * D_ * 2;
  __hip_bfloat16* W2p = (__hip_bfloat16*)ws; ws += (size_t)H_ * H_ * 2;
  __hip_bfloat16* W3p = (__hip_bfloat16*)ws; ws += (size_t)D_ * H_ * 2;
  __hip_bfloat16* W1t = (__hip_bfloat16*)ws; ws += (size_t)H_ * D_ * 2;
  __hip_bfloat16* W2t = (__hip_bfloat16*)ws; ws += (size_t)H_ * H_ * 2;
  __hip_bfloat16* W3t = (__hip_bfloat16*)ws; ws += (size_t)D_ * H_ * 2;
  float* bf1  = (float*)ws;                  ws += (size_t)H_ * 4;
  float* bf2  = (float*)ws;                  ws += (size_t)H_ * 4;
  float* bf3  = (float*)ws;                  ws += (size_t)D_ * 4;
  float* dts  = (float*)ws;                  ws += 64 * 4;
  int*   flags= (int*)ws;                    ws += 64 * 4;

  detect_k<<<1, 64, 0, stream>>>(tarr, W2, dts, flags, d_out);
  dim3 tb(32, 8);
  transpose_k<<<dim3(H_ / 32, D_ / 32), tb, 0, stream>>>(W1, W1t, D_, H_, flags);
  transpose_k<<<dim3(H_ / 32, H_ / 32), tb, 0, stream>>>(W2, W2t, H_, H_, flags);
  transpose_k<<<dim3(D_ / 32, H_ / 32), tb, 0, stream>>>(W3, W3t, H_, D_, flags);
  prep_bias_k<<<H_ / 256, 256, 0, stream>>>(b1, b2, b3, bf1, bf2, bf3, flags);
  pack_k<<<(H_ * D_ / 8) / 256, 256, 0, stream>>>(W1t, W1p, D_, 8);
  pack_k<<<(H_ * H_ / 8) / 256, 256, 0, stream>>>(W2t, W2p, H_, 8);
  pack_k<<<(D_ * H_ / 8) / 256, 256, 0, stream>>>(W3t, W3p, H_, 2);
  ode_k<<<M_ / 16, 512, 0, stream>>>(fp, W1p, W2p, W3p, bf1, bf2, bf3,
                                     dts, flags, d_out);
}